// Round 9
// baseline (315.141 us; speedup 1.0000x reference)
//
#include <hip/hip_runtime.h>
#include <hip/hip_bf16.h>

// Problem constants
#define PN 16384
#define PZ 100
#define PE 400
#define PM0 4000
#define PM1 2000
#define KP 128            // packed K: [0,100) = f16 data, [100,128) = zero
#define SEG1ROW 4096      // B2T row base of segment 1
#define MROWS 6144        // 4096 (seg0 pad) + 2048 (seg1 pad)

typedef __attribute__((ext_vector_type(8))) _Float16 half8v;
typedef __attribute__((ext_vector_type(4))) float floatx4;
typedef __attribute__((ext_vector_type(4))) unsigned int uint4v;

// ---------------------------------------------------------------------------
// zero-fill B2T: k-pads MUST be zero (they feed MFMA); pad rows made finite.
// ---------------------------------------------------------------------------
__global__ __launch_bounds__(256) void fill_kernel(uint4v* __restrict__ p, int n16)
{
    int i = blockIdx.x * 256 + threadIdx.x;
    if (i < n16) p[i] = (uint4v){0u, 0u, 0u, 0u};
}

// ---------------------------------------------------------------------------
// topic (both segments, one dispatch):
// b2t[rowbase+m][z] = f16( sum_e beta[z][e] * alpha[m][e] )
// ---------------------------------------------------------------------------
__global__ __launch_bounds__(256) void topic_kernel(
    const float* __restrict__ alpha0, const float* __restrict__ alpha1,
    const float* __restrict__ beta, _Float16* __restrict__ b2t)
{
    const int seg = (blockIdx.x >= 64);
    const int tile = seg ? (blockIdx.x - 64) : blockIdx.x;
    const float* alpha = seg ? alpha1 : alpha0;
    const int M = seg ? PM1 : PM0;
    const int rowbase = seg ? SEG1ROW : 0;

    __shared__ float sA[64][201];
    const int tid = threadIdx.x;
    const int ml = tid & 63;
    const int zt = tid >> 6;
    const int m0 = tile * 64;
    const int z0 = blockIdx.y * 20 + zt * 5;

    float acc[5] = {0.f, 0.f, 0.f, 0.f, 0.f};

    for (int ec = 0; ec < 2; ++ec) {
        #pragma unroll
        for (int l = 0; l < 50; ++l) {
            int idx = tid + l * 256;
            int mr = idx / 200;
            int e  = idx - mr * 200;
            int m  = m0 + mr;
            sA[mr][e] = (m < M) ? alpha[(size_t)m * PE + ec * 200 + e] : 0.f;
        }
        __syncthreads();
        const float* bz = beta + (size_t)z0 * PE + ec * 200;
        #pragma unroll 4
        for (int e = 0; e < 200; ++e) {
            float a = sA[ml][e];
            #pragma unroll
            for (int zi = 0; zi < 5; ++zi)
                acc[zi] = fmaf(bz[zi * PE + e], a, acc[zi]);
        }
        __syncthreads();
    }
    int m = m0 + ml;
    if (m < M) {
        #pragma unroll
        for (int zi = 0; zi < 5; ++zi)
            b2t[(size_t)(rowbase + m) * KP + (z0 + zi)] = (_Float16)acc[zi];
    }
}

// ---------------------------------------------------------------------------
// Fused GEMM + LSE + writeout, v3 (defer-max fixed: store raw v, never
// reconstruct from the huge initial max).
// 512 blocks x 512 threads (8 waves). Block owns 32 rows x BOTH segments
// (uniform work -> flat occupancy). Tile = 128 cols; wave w covers cols
// [w*16, w*16+16). B fragments loaded DIRECTLY from L2-resident B2T into
// registers (no LDS, no barriers, no bank conflicts in the sweeps).
// ---------------------------------------------------------------------------
__global__ __launch_bounds__(512, 4) void fused_kernel(
    const float* __restrict__ theta,
    const _Float16* __restrict__ B2T,
    const float* __restrict__ bias0, const float* __restrict__ bias1,
    const int* __restrict__ dom,
    float* __restrict__ out0, float* __restrict__ out1)
{
    __shared__ __align__(1024) char sA[8192];   // 32 rows x 128 k f16, swizzled
    __shared__ float smx[8][32];
    __shared__ float sms[8][32];
    __shared__ float slse[32];

    const int tid = threadIdx.x;
    const int w   = tid >> 6;     // 0..7
    const int ll  = tid & 63;
    const int g   = ll >> 4;      // 0..3
    const int c   = ll & 15;      // 0..15
    const int n0  = blockIdx.x * 32;

    // ---- stage A panel: theta f32 -> f16 (512 threads = 32 rows x 16 slots) ----
    {
        int row  = tid >> 4;
        int slot = tid & 15;
        const float* tr = theta + (size_t)(n0 + row) * PZ + slot * 8;
        half8v h;
        if (slot < 12) {
            float4 lo = *(const float4*)tr;
            float4 hi = *(const float4*)(tr + 4);
            h[0] = (_Float16)lo.x; h[1] = (_Float16)lo.y;
            h[2] = (_Float16)lo.z; h[3] = (_Float16)lo.w;
            h[4] = (_Float16)hi.x; h[5] = (_Float16)hi.y;
            h[6] = (_Float16)hi.z; h[7] = (_Float16)hi.w;
        } else if (slot == 12) {
            float4 lo = *(const float4*)tr;   // k = 96..99
            h[0] = (_Float16)lo.x; h[1] = (_Float16)lo.y;
            h[2] = (_Float16)lo.z; h[3] = (_Float16)lo.w;
            h[4] = (_Float16)0.f; h[5] = (_Float16)0.f;
            h[6] = (_Float16)0.f; h[7] = (_Float16)0.f;
        } else {
            h = (half8v)(_Float16)0.f;
        }
        *(half8v*)(sA + row * 256 + ((slot ^ (row & 7)) * 16)) = h;
    }
    __syncthreads();

    // ---- A fragments -> registers (held for all sweeps) ----
    half8v aF[2][4];
    #pragma unroll
    for (int mi = 0; mi < 2; ++mi) {
        int row = mi * 16 + c;
        #pragma unroll
        for (int kb = 0; kb < 4; ++kb) {
            int slot = (kb * 4 + g) ^ (row & 7);
            aF[mi][kb] = *(const half8v*)(sA + row * 256 + slot * 16);
        }
    }

    // ---- per-lane row domains (row-constant: hoisted out of all sweeps) ----
    int drow[2][4];
    #pragma unroll
    for (int mi = 0; mi < 2; ++mi)
        #pragma unroll
        for (int i = 0; i < 4; ++i)
            drow[mi][i] = dom[n0 + mi * 16 + 4 * g + i];

    for (int seg = 0; seg < 2; ++seg) {
        const int Mse = seg ? PM1 : PM0;
        const int NT  = seg ? 16 : 32;                    // 128-col tiles
        const _Float16* Bseg = B2T + (size_t)(seg ? SEG1ROW : 0) * KP;
        const float* bias = seg ? bias1 : bias0;
        float* out = seg ? out1 : out0;

        const _Float16* bcol = Bseg + (size_t)(w * 16 + c) * KP;   // lane's B row
        const int mbase = w * 16 + c;

        float mx_[2][4], sm_[2][4];
        #pragma unroll
        for (int mi = 0; mi < 2; ++mi)
            #pragma unroll
            for (int i = 0; i < 4; ++i) { mx_[mi][i] = -3.0e38f; sm_[mi][i] = 0.f; }

        // =========== stats sweep (barrier-free) ===========
        for (int t = 0; t < NT; ++t) {
            const int m  = t * 128 + mbase;
            const _Float16* bp = bcol + (size_t)t * 128 * KP;
            half8v bF[4];
            #pragma unroll
            for (int kb = 0; kb < 4; ++kb)
                bF[kb] = *(const half8v*)(bp + kb * 32 + g * 8);

            const bool mv = (m < Mse);
            const int mc = mv ? m : (Mse - 1);
            float bv0 = bias[mc];
            float bv1 = bias[(size_t)Mse + mc];
            float bv2 = bias[2 * (size_t)Mse + mc];
            float bv3 = bias[3 * (size_t)Mse + mc];

            floatx4 acc[2];
            acc[0] = (floatx4){0.f, 0.f, 0.f, 0.f};
            acc[1] = (floatx4){0.f, 0.f, 0.f, 0.f};
            #pragma unroll
            for (int mi = 0; mi < 2; ++mi)
                #pragma unroll
                for (int kb = 0; kb < 4; ++kb)
                    acc[mi] = __builtin_amdgcn_mfma_f32_16x16x32_f16(
                        aF[mi][kb], bF[kb], acc[mi], 0, 0, 0);

            // defer-max online stats: vv holds the RAW value (no reconstruction)
            float vv[2][4];
            float gm = -3.0e38f;
            #pragma unroll
            for (int mi = 0; mi < 2; ++mi) {
                #pragma unroll
                for (int i = 0; i < 4; ++i) {
                    int d = drow[mi][i];
                    float bv = (d < 2) ? (d == 0 ? bv0 : bv1) : (d == 2 ? bv2 : bv3);
                    float v = mv ? (acc[mi][i] + bv) : -1.0e30f;
                    vv[mi][i] = v;
                    gm = fmaxf(gm, v - mx_[mi][i]);
                }
            }
            if (gm <= 8.0f) {
                // fast path: max unchanged, 1 exp/elem
                #pragma unroll
                for (int mi = 0; mi < 2; ++mi)
                    #pragma unroll
                    for (int i = 0; i < 4; ++i)
                        sm_[mi][i] += __expf(vv[mi][i] - mx_[mi][i]);
            } else {
                #pragma unroll
                for (int mi = 0; mi < 2; ++mi) {
                    #pragma unroll
                    for (int i = 0; i < 4; ++i) {
                        float v  = vv[mi][i];
                        float nm = fmaxf(mx_[mi][i], v);
                        sm_[mi][i] = sm_[mi][i] * __expf(mx_[mi][i] - nm)
                                   + __expf(v - nm);
                        mx_[mi][i] = nm;
                    }
                }
            }
        }

        // =========== reduce -> per-row LSE ===========
        #pragma unroll
        for (int mi = 0; mi < 2; ++mi) {
            #pragma unroll
            for (int i = 0; i < 4; ++i) {
                float m_ = mx_[mi][i], s_ = sm_[mi][i];
                #pragma unroll
                for (int msk = 1; msk < 16; msk <<= 1) {
                    float mo = __shfl_xor(m_, msk);
                    float so = __shfl_xor(s_, msk);
                    float nm = fmaxf(m_, mo);
                    s_ = s_ * __expf(m_ - nm) + so * __expf(mo - nm);
                    m_ = nm;
                }
                if (c == 0) {
                    int row = mi * 16 + 4 * g + i;
                    smx[w][row] = m_;
                    sms[w][row] = s_;
                }
            }
        }
        __syncthreads();
        if (tid < 32) {
            float m_ = smx[0][tid], s_ = sms[0][tid];
            #pragma unroll
            for (int wv = 1; wv < 8; ++wv) {
                float mo = smx[wv][tid];
                float so = sms[wv][tid];
                float nm = fmaxf(m_, mo);
                s_ = s_ * __expf(m_ - nm) + so * __expf(mo - nm);
                m_ = nm;
            }
            slse[tid] = m_ + __logf(s_);
        }
        __syncthreads();
        float lse_[2][4];
        #pragma unroll
        for (int mi = 0; mi < 2; ++mi)
            #pragma unroll
            for (int i = 0; i < 4; ++i)
                lse_[mi][i] = slse[mi * 16 + 4 * g + i];
        __syncthreads();   // all lanes done with slse before next seg reuses it

        // =========== write sweep (barrier-free, recompute) ===========
        for (int t = 0; t < NT; ++t) {
            const int m  = t * 128 + mbase;
            const _Float16* bp = bcol + (size_t)t * 128 * KP;
            half8v bF[4];
            #pragma unroll
            for (int kb = 0; kb < 4; ++kb)
                bF[kb] = *(const half8v*)(bp + kb * 32 + g * 8);

            const bool mv = (m < Mse);
            const int mc = mv ? m : (Mse - 1);
            float bv0 = bias[mc];
            float bv1 = bias[(size_t)Mse + mc];
            float bv2 = bias[2 * (size_t)Mse + mc];
            float bv3 = bias[3 * (size_t)Mse + mc];

            floatx4 acc[2];
            acc[0] = (floatx4){0.f, 0.f, 0.f, 0.f};
            acc[1] = (floatx4){0.f, 0.f, 0.f, 0.f};
            #pragma unroll
            for (int mi = 0; mi < 2; ++mi)
                #pragma unroll
                for (int kb = 0; kb < 4; ++kb)
                    acc[mi] = __builtin_amdgcn_mfma_f32_16x16x32_f16(
                        aF[mi][kb], bF[kb], acc[mi], 0, 0, 0);

            if (mv) {
                #pragma unroll
                for (int mi = 0; mi < 2; ++mi) {
                    #pragma unroll
                    for (int i = 0; i < 4; ++i) {
                        int row = mi * 16 + 4 * g + i;
                        int d = drow[mi][i];
                        float bv = (d < 2) ? (d == 0 ? bv0 : bv1)
                                           : (d == 2 ? bv2 : bv3);
                        float o = acc[mi][i] + bv - lse_[mi][i];
                        __builtin_nontemporal_store(
                            o, &out[(size_t)(n0 + row) * Mse + m]);
                    }
                }
            }
        }
    }
}

// ---------------------------------------------------------------------------
extern "C" void kernel_launch(void* const* d_in, const int* in_sizes, int n_in,
                              void* d_out, int out_size, void* d_ws, size_t ws_size,
                              hipStream_t stream) {
    const float* theta  = (const float*)d_in[0];
    const float* alpha0 = (const float*)d_in[1];
    const float* alpha1 = (const float*)d_in[2];
    const float* beta   = (const float*)d_in[3];
    const float* bias0  = (const float*)d_in[4];
    const float* bias1  = (const float*)d_in[5];
    const int*   dom    = (const int*)d_in[6];

    float* out0 = (float*)d_out;
    float* out1 = out0 + (size_t)PN * PM0;

    _Float16* B2T = (_Float16*)d_ws;   // [MROWS][KP] f16, 1.57 MB

    // 1. zero B2T (k-pads feed MFMA and must be 0; pad rows made finite)
    {
        int n16 = MROWS * KP * 2 / 16;
        fill_kernel<<<(n16 + 255) / 256, 256, 0, stream>>>((uint4v*)B2T, n16);
    }

    // 2. topics (both segments) -> B2T f16 transposed
    topic_kernel<<<dim3(96, 5), 256, 0, stream>>>(alpha0, alpha1, beta, B2T);

    // 3. fused GEMM + LSE + writeout: 512 uniform blocks, 2/CU, 16 waves/CU
    fused_kernel<<<PN / 32, 512, 0, stream>>>(
        theta, B2T, bias0, bias1, dom, out0, out1);
}